// Round 1
// 938.009 us; speedup vs baseline: 2.6247x; 2.6247x over previous
//
#include <hip/hip_runtime.h>

// DeepSet: N=1M nodes, G=10k graphs (sorted segment ids), HIDDEN=50, 2 layers.
// This version replaces the VALU matvec chain in k_layer with MFMA
// (v_mfma_f32_16x16x32_bf16) using an fp32-emulating bf16 hi/lo truncation
// split: y = x_hi@W_hi + x_lo@W_hi + x_hi@W_lo  (err ~2^-16 rel).
// W fragments (hi/lo, zero-padded 50->64 in j and k) are precomputed once by
// k_wfrag into B-fragment layout, so k_layer does no weight LDS staging at all.
// Per-wave-private swizzled LDS x-tile -> zero __syncthreads in k_layer.

#define GN 10000
#define H 50
#define EPSV 1e-5f

typedef __attribute__((ext_vector_type(8))) short short8;
typedef __attribute__((ext_vector_type(4))) float f32x4;

__global__ void k_start(const int* __restrict__ sid, int N, int* __restrict__ start){
  int g = blockIdx.x*blockDim.x + threadIdx.x;
  if (g > GN) return;
  int lo = 0, hi = N;
  while (lo < hi){ int mid = (lo+hi)>>1; if (sid[mid] < g) lo = mid+1; else hi = mid; }
  start[g] = lo;
}

__global__ void k_gsum_xy(const float2* __restrict__ xy, const int* __restrict__ start,
                          float* __restrict__ gxy){
  int g = blockIdx.x; int l = threadIdx.x;   // 64 threads = 1 wave
  int s = start[g], e = start[g+1];
  float sx = 0.f, sy = 0.f;
  for (int n = s + l; n < e; n += 64){ float2 v = xy[n]; sx += v.x; sy += v.y; }
  #pragma unroll
  for (int off = 32; off > 0; off >>= 1){ sx += __shfl_down(sx, off); sy += __shfl_down(sy, off); }
  if (l == 0){ gxy[2*g] = sx; gxy[2*g+1] = sy; }
}

template<int LAYER>
__global__ void k_tgraph(const float* __restrict__ gxy, const float* __restrict__ gsum,
                         const int* __restrict__ start,
                         const float* __restrict__ w_init, const float* __restrict__ b_init,
                         const float* __restrict__ Ws1, const float* __restrict__ bs1,
                         const float* __restrict__ stats, float* __restrict__ tg){
  __shared__ float glob[H];
  int g = blockIdx.x; int j = threadIdx.x;   // 64 threads
  int cnt = start[g+1] - start[g]; if (cnt < 1) cnt = 1;
  float inv = 1.f/(float)cnt;
  if (j < H){
    if (LAYER == 0){
      float mx = gxy[2*g]*inv, my = gxy[2*g+1]*inv;
      glob[j] = b_init[j] + mx*w_init[j] + my*w_init[H+j];
    } else {
      glob[j] = gsum[g*H+j]*inv*stats[j] + stats[H+j];   // a1, c1
    }
  }
  __syncthreads();
  if (j < H){
    const float* W = Ws1 + LAYER*100*H;   // rows 0..49 multiply glob
    float acc = bs1[LAYER*H + j];
    #pragma unroll 5
    for (int k = 0; k < H; ++k) acc = fmaf(glob[k], W[k*H + j], acc);
    tg[g*H + j] = acc;
  }
}

// ---- precompute W as MFMA B-fragments, bf16 hi/lo truncation split ----
// layout (short8 units): [(L*5+m)*16 + jt*4 + kk][lane]   kk: 0=hi ks0,1=hi ks1,2=lo ks0,3=lo ks1
__global__ void k_wfrag(const float* __restrict__ Ws1, const float* __restrict__ Ws,
                        unsigned int* __restrict__ frag){
  int t = blockIdx.x*blockDim.x + threadIdx.x;     // 2L * 5m * 4jt * 4kk * 64lane = 10240
  if (t >= 2*5*4*4*64) return;
  int lane = t & 63;
  int kk   = (t>>6) & 3;
  int jt   = (t>>8) & 3;
  int m    = (t>>10) % 5;
  int L    = t / (5*4*4*64);
  const float* W = (m == 0) ? (Ws1 + L*100*H + H*H) : (Ws + L*4*H*H + (m-1)*H*H);
  int ks = kk & 1;
  int lo = kk >> 1;
  int kbase = ks*32 + (lane>>4)*8;
  int j = jt*16 + (lane&15);
  unsigned int* dst = frag + (size_t)t*4;
  #pragma unroll
  for (int w = 0; w < 4; ++w){
    unsigned int bits[2];
    #pragma unroll
    for (int e = 0; e < 2; ++e){
      int k = kbase + w*2 + e;
      float v = (k < H && j < H) ? W[k*H + j] : 0.f;   // zero-pad kills 50->64 pad columns
      unsigned int u = __float_as_uint(v);
      unsigned int out;
      if (!lo) out = u >> 16;                            // truncated hi
      else {
        float res = v - __uint_as_float(u & 0xFFFF0000u);
        out = __float_as_uint(res) >> 16;                // truncated residual
      }
      bits[e] = out & 0xFFFFu;
    }
    dst[w] = (bits[1] << 16) | bits[0];
  }
}

template<int LAYER>
__global__ __launch_bounds__(256, 2)
void k_layer(const float2* __restrict__ xy, const int* __restrict__ sid,
             const float* __restrict__ tg, const unsigned int* __restrict__ frag,
             const float* __restrict__ bs,
             const float* __restrict__ w_init, const float* __restrict__ b_init,
             const float* __restrict__ stats,
             float* __restrict__ xio, int N)
{
  // per-wave x tile: [wave][plane hi/lo][node 0..63][k 0..63] bf16, XOR-swizzled in k
  __shared__ __align__(16) unsigned short xs[4][2][64][64];    // 64 KiB
  const int tid = threadIdx.x;
  const int wv = tid >> 6;
  const int l  = tid & 63;
  const int lg = l >> 4;        // lane group (0..3)
  const int ll = l & 15;
  const int base = blockIdx.x*256 + wv*64;   // this wave's first node

  // per-lane constants (j = jt*16 + ll), masked to 0 for j >= 50
  float bias_r[4][4];
  #pragma unroll
  for (int m = 0; m < 4; ++m)
    #pragma unroll
    for (int jt = 0; jt < 4; ++jt){
      int j = jt*16 + ll;
      bias_r[m][jt] = (j < H) ? bs[LAYER*4*H + m*H + j] : 0.f;
    }
  float p0[4], p1[4], p2c[4];
  #pragma unroll
  for (int jt = 0; jt < 4; ++jt){
    int j = jt*16 + ll;
    if (LAYER == 0){
      p0[jt]  = (j < H) ? w_init[j]   : 0.f;
      p1[jt]  = (j < H) ? w_init[H+j] : 0.f;
      p2c[jt] = (j < H) ? b_init[j]   : 0.f;
    } else {
      p0[jt]  = (j < H) ? stats[j]    : 0.f;   // a1
      p1[jt]  = 0.f;
      p2c[jt] = (j < H) ? stats[H+j]  : 0.f;   // c1
    }
  }

  // matvec-0 accumulator init = tg[g]  (per-graph glob part + bias, fp32-exact)
  f32x4 acc[4][4];   // [Mt][jt], C layout: col j = jt*16+ll, row node = Mt*16 + lg*4 + r
  #pragma unroll
  for (int Mt = 0; Mt < 4; ++Mt)
    #pragma unroll
    for (int r = 0; r < 4; ++r){
      int node = base + Mt*16 + lg*4 + r;
      int nc = (node < N) ? node : (N-1);
      int g = sid[nc];
      const float* tr = tg + (size_t)g*H;
      #pragma unroll
      for (int jt = 0; jt < 4; ++jt){
        int j = jt*16 + ll;
        acc[Mt][jt][r] = (j < H) ? tr[j] : 0.f;
      }
    }

  // stage matvec-0 input (L0: h0 = b + xy@w_init ; L1: BN1-affined x1) -> split -> LDS
  #pragma unroll
  for (int Mt = 0; Mt < 4; ++Mt)
    #pragma unroll
    for (int r = 0; r < 4; ++r){
      int node = base + Mt*16 + lg*4 + r;
      int nl = Mt*16 + lg*4 + r;
      float ax = 0.f, ay = 0.f;
      if (LAYER == 0){
        if (node < N){ float2 v = xy[node]; ax = v.x; ay = v.y; }
      }
      #pragma unroll
      for (int jt = 0; jt < 4; ++jt){
        int j = jt*16 + ll;
        float v;
        if (LAYER == 0){
          v = p2c[jt] + ax*p0[jt] + ay*p1[jt];
        } else {
          float t = (node < N && j < H) ? xio[(size_t)node*H + j] : 0.f;
          v = t*p0[jt] + p2c[jt];
        }
        int ke = j ^ ((nl & 7) << 3);
        unsigned int u = __float_as_uint(v);
        xs[wv][0][nl][ke] = (unsigned short)(u >> 16);
        float res = v - __uint_as_float(u & 0xFFFF0000u);
        xs[wv][1][nl][ke] = (unsigned short)(__float_as_uint(res) >> 16);
      }
    }

  // ---- 5 chained matvecs, all MFMA, no barriers (LDS tile is wave-private) ----
  #pragma unroll
  for (int m = 0; m < 5; ++m){
    const short8* fp = (const short8*)frag + (size_t)(LAYER*5 + m)*16*64;

    if (m > 0){
      // relu(prev output) -> hi/lo split -> scatter to LDS; reset acc to bias
      #pragma unroll
      for (int Mt = 0; Mt < 4; ++Mt)
        #pragma unroll
        for (int r = 0; r < 4; ++r){
          int nl = Mt*16 + lg*4 + r;
          #pragma unroll
          for (int jt = 0; jt < 4; ++jt){
            int j = jt*16 + ll;
            float v = fmaxf(acc[Mt][jt][r], 0.f);
            int ke = j ^ ((nl & 7) << 3);
            unsigned int u = __float_as_uint(v);
            xs[wv][0][nl][ke] = (unsigned short)(u >> 16);
            float res = v - __uint_as_float(u & 0xFFFF0000u);
            xs[wv][1][nl][ke] = (unsigned short)(__float_as_uint(res) >> 16);
            acc[Mt][jt][r] = bias_r[m-1][jt];
          }
        }
    }

    // A fragments: row = ll (node), k = lg*8.. ; swizzle uses nl&7 == ll&7
    short8 af[4][4];   // [Mt][kk] kk: 0=hi ks0,1=hi ks1,2=lo ks0,3=lo ks1
    #pragma unroll
    for (int Mt = 0; Mt < 4; ++Mt){
      int nl = Mt*16 + ll;
      #pragma unroll
      for (int kk = 0; kk < 4; ++kk){
        int p = kk >> 1, ks = kk & 1;
        int e0 = (ks*32 + lg*8) ^ ((ll & 7) << 3);
        af[Mt][kk] = *(const short8*)&xs[wv][p][nl][e0];
      }
    }

    // jt loop with one-ahead B prefetch (B frags straight from global, L1-resident)
    short8 b0 = fp[0*64 + l];
    short8 b1 = fp[1*64 + l];
    short8 b2 = fp[2*64 + l];
    short8 b3 = fp[3*64 + l];
    #pragma unroll
    for (int jt = 0; jt < 4; ++jt){
      short8 n0, n1, n2, n3;
      if (jt < 3){
        n0 = fp[((jt+1)*4+0)*64 + l];
        n1 = fp[((jt+1)*4+1)*64 + l];
        n2 = fp[((jt+1)*4+2)*64 + l];
        n3 = fp[((jt+1)*4+3)*64 + l];
      }
      #pragma unroll
      for (int Mt = 0; Mt < 4; ++Mt){
        f32x4 c = acc[Mt][jt];
        c = __builtin_amdgcn_mfma_f32_16x16x32_bf16(af[Mt][0], b0, c, 0, 0, 0); // hi@Whi ks0
        c = __builtin_amdgcn_mfma_f32_16x16x32_bf16(af[Mt][1], b1, c, 0, 0, 0); // hi@Whi ks1
        c = __builtin_amdgcn_mfma_f32_16x16x32_bf16(af[Mt][2], b0, c, 0, 0, 0); // lo@Whi ks0
        c = __builtin_amdgcn_mfma_f32_16x16x32_bf16(af[Mt][3], b1, c, 0, 0, 0); // lo@Whi ks1
        c = __builtin_amdgcn_mfma_f32_16x16x32_bf16(af[Mt][0], b2, c, 0, 0, 0); // hi@Wlo ks0
        c = __builtin_amdgcn_mfma_f32_16x16x32_bf16(af[Mt][1], b3, c, 0, 0, 0); // hi@Wlo ks1
        acc[Mt][jt] = c;
      }
      if (jt < 3){ b0 = n0; b1 = n1; b2 = n2; b3 = n3; }
    }
  }

  // store matvec-5 output (no relu); 16-lane j-runs are 64B-coalesced
  #pragma unroll
  for (int Mt = 0; Mt < 4; ++Mt)
    #pragma unroll
    for (int r = 0; r < 4; ++r){
      int node = base + Mt*16 + lg*4 + r;
      if (node < N){
        #pragma unroll
        for (int jt = 0; jt < 4; ++jt){
          int j = jt*16 + ll;
          if (j < H) xio[(size_t)node*H + j] = acc[Mt][jt][r];
        }
      }
    }
}

__global__ void k_stats(const float* __restrict__ x, const int* __restrict__ start,
                        float* __restrict__ gsum, float* __restrict__ psum,
                        float* __restrict__ psq){
  int g = blockIdx.x; int j = threadIdx.x;   // 64 threads, 50 active
  if (j >= H) return;
  int s = start[g], e = start[g+1];
  float acc = 0.f, q = 0.f;
  for (int n = s; n < e; ++n){ float v = x[n*H + j]; acc += v; q = fmaf(v, v, q); }
  gsum[g*H + j] = acc;
  int slot = g & 63;
  atomicAdd(&psum[slot*H + j], acc);
  atomicAdd(&psq[slot*H + j], q);
}

__global__ void k_finalize(const float* __restrict__ psum, const float* __restrict__ psq,
                           const float* __restrict__ gamma, const float* __restrict__ beta,
                           int layer, float ninv, float* __restrict__ stats){
  int j = threadIdx.x;
  if (j >= H) return;
  float s = 0.f, q = 0.f;
  #pragma unroll 8
  for (int p = 0; p < 64; ++p){ s += psum[p*H + j]; q += psq[p*H + j]; }
  float mu  = s*ninv;
  float var = q*ninv - mu*mu;
  float a = rsqrtf(var + EPSV) * gamma[layer*H + j];
  float c = beta[layer*H + j] - mu*a;
  stats[layer*100 + j]     = a;
  stats[layer*100 + H + j] = c;
}

__global__ void k_bnapply(float* __restrict__ x, const float* __restrict__ stats, int N){
  __shared__ float a[H], c[H];
  if (threadIdx.x < H){ a[threadIdx.x] = stats[100 + threadIdx.x]; c[threadIdx.x] = stats[150 + threadIdx.x]; }
  __syncthreads();
  int base = blockIdx.x * (256*H);    // block covers 256 nodes -> base % 50 == 0
  int total = N*H;
  for (int idx = threadIdx.x; idx < 256*H; idx += 256){
    int i = base + idx;
    if (i < total){
      int j = idx - (idx/H)*H;
      x[i] = x[i]*a[j] + c[j];
    }
  }
}

extern "C" void kernel_launch(void* const* d_in, const int* in_sizes, int n_in,
                              void* d_out, int out_size, void* d_ws, size_t ws_size,
                              hipStream_t stream) {
  const float2* xy     = (const float2*)d_in[0];
  const int*    sid    = (const int*)d_in[1];
  const float*  w_init = (const float*)d_in[3];
  const float*  b_init = (const float*)d_in[4];
  const float*  Ws1    = (const float*)d_in[5];
  const float*  bs1    = (const float*)d_in[6];
  const float*  Ws     = (const float*)d_in[7];
  const float*  bs     = (const float*)d_in[8];
  const float*  gamma  = (const float*)d_in[9];
  const float*  beta   = (const float*)d_in[10];
  float* out = (float*)d_out;
  int N = in_sizes[0] / 2;
  const int G = GN;

  char* ws = (char*)d_ws;
  int*   start = (int*)ws;                          // (G+1) ints
  float* gxy   = (float*)(ws + 40064);              // 2G floats
  float* tg    = (float*)(ws + 120064);             // 50G floats (2 MB)
  float* gsum  = (float*)(ws + 2120064);            // 50G floats (2 MB)
  float* psum  = (float*)(ws + 4120064);            // 64*50 floats
  float* psq   = (float*)(ws + 4132864);            // 64*50 floats
  float* stats = (float*)(ws + 4145664);            // 200 floats: a1,c1,a2,c2
  unsigned int* wfrag = (unsigned int*)(ws + 4147200); // 163840 B of W fragments

  int nb = (N + 255)/256;

  k_wfrag<<<40, 256, 0, stream>>>(Ws1, Ws, wfrag);
  k_start<<<(G + 1 + 255)/256, 256, 0, stream>>>(sid, N, start);
  k_gsum_xy<<<G, 64, 0, stream>>>(xy, start, gxy);
  k_tgraph<0><<<G, 64, 0, stream>>>(gxy, gsum, start, w_init, b_init, Ws1, bs1, stats, tg);
  k_layer<0><<<nb, 256, 0, stream>>>(xy, sid, tg, wfrag, bs, w_init, b_init, stats, out, N);

  hipMemsetAsync(psum, 0, 2*64*H*sizeof(float), stream);   // psum+psq contiguous
  k_stats<<<G, 64, 0, stream>>>(out, start, gsum, psum, psq);
  k_finalize<<<1, 64, 0, stream>>>(psum, psq, gamma, beta, 0, 1.0f/(float)N, stats);

  k_tgraph<1><<<G, 64, 0, stream>>>(gxy, gsum, start, w_init, b_init, Ws1, bs1, stats, tg);
  k_layer<1><<<nb, 256, 0, stream>>>(xy, sid, tg, wfrag, bs, w_init, b_init, stats, out, N);

  hipMemsetAsync(psum, 0, 2*64*H*sizeof(float), stream);
  k_stats<<<G, 64, 0, stream>>>(out, start, gsum, psum, psq);
  k_finalize<<<1, 64, 0, stream>>>(psum, psq, gamma, beta, 1, 1.0f/(float)N, stats);

  k_bnapply<<<(N + 255)/256, 256, 0, stream>>>(out, stats, N);
}

// Round 3
// 839.521 us; speedup vs baseline: 2.9326x; 1.1173x over previous
//
#include <hip/hip_runtime.h>

// DeepSet: N=1M nodes, G=10k graphs (sorted segment ids), HIDDEN=50, 2 layers.
// k_layer v3: transposed-orientation MFMA chain, D = W^T x^T via
// v_mfma_f32_16x16x16_f16. The 16x16x16 shape's C/D row granularity (4/lane
// group) equals the B-operand k granularity (4/lane group), so each matvec's
// output registers (relu + cvt_pkrtz hi/lo split) ARE the next matvec's
// B-fragments in-place: no LDS, no shuffles, no barriers in k_layer.
// fp32 emulated as f16 3-product: y = xh@Wh + xl@Wh + xh@Wl (rel err ~2^-20).
// W^T fragments (hi/lo planes, zero-padded 50->64) precomputed by k_wfrag.

#define GN 10000
#define H 50
#define EPSV 1e-5f

typedef __attribute__((ext_vector_type(4))) float f32x4;
typedef __attribute__((ext_vector_type(2))) __fp16 fp16x2;
typedef __attribute__((ext_vector_type(4))) _Float16 half4_t;

union H4 { half4_t h; uint2 u; };

static __device__ __forceinline__ f32x4 mfma16(half4_t a, half4_t b, f32x4 c){
#if __has_builtin(__builtin_amdgcn_mfma_f32_16x16x16f16)
  return __builtin_amdgcn_mfma_f32_16x16x16f16(a, b, c, 0, 0, 0);
#else
  asm volatile("v_mfma_f32_16x16x16_f16 %0, %1, %2, %0" : "+v"(c) : "v"(a), "v"(b));
  return c;
#endif
}

// split fp32x4 into f16 hi plane + f16 residual plane (RTZ/RN -> residual path exact)
static __device__ __forceinline__ void split4(f32x4 v, H4& hh, H4& hl){
  fp16x2 a = __builtin_amdgcn_cvt_pkrtz(v[0], v[1]);
  fp16x2 b = __builtin_amdgcn_cvt_pkrtz(v[2], v[3]);
  hh.u.x = __builtin_bit_cast(unsigned int, a);
  hh.u.y = __builtin_bit_cast(unsigned int, b);
  float r0 = v[0] - (float)a[0];
  float r1 = v[1] - (float)a[1];
  float r2 = v[2] - (float)b[0];
  float r3 = v[3] - (float)b[1];
  fp16x2 c = __builtin_amdgcn_cvt_pkrtz(r0, r1);
  fp16x2 d = __builtin_amdgcn_cvt_pkrtz(r2, r3);
  hl.u.x = __builtin_bit_cast(unsigned int, c);
  hl.u.y = __builtin_bit_cast(unsigned int, d);
}

__global__ void k_start(const int* __restrict__ sid, int N, int* __restrict__ start){
  int g = blockIdx.x*blockDim.x + threadIdx.x;
  if (g > GN) return;
  int lo = 0, hi = N;
  while (lo < hi){ int mid = (lo+hi)>>1; if (sid[mid] < g) lo = mid+1; else hi = mid; }
  start[g] = lo;
}

__global__ void k_gsum_xy(const float2* __restrict__ xy, const int* __restrict__ start,
                          float* __restrict__ gxy){
  int g = blockIdx.x; int l = threadIdx.x;   // 64 threads = 1 wave
  int s = start[g], e = start[g+1];
  float sx = 0.f, sy = 0.f;
  for (int n = s + l; n < e; n += 64){ float2 v = xy[n]; sx += v.x; sy += v.y; }
  #pragma unroll
  for (int off = 32; off > 0; off >>= 1){ sx += __shfl_down(sx, off); sy += __shfl_down(sy, off); }
  if (l == 0){ gxy[2*g] = sx; gxy[2*g+1] = sy; }
}

template<int LAYER>
__global__ void k_tgraph(const float* __restrict__ gxy, const float* __restrict__ gsum,
                         const int* __restrict__ start,
                         const float* __restrict__ w_init, const float* __restrict__ b_init,
                         const float* __restrict__ Ws1, const float* __restrict__ bs1,
                         const float* __restrict__ stats, float* __restrict__ tg){
  __shared__ float glob[H];
  int g = blockIdx.x; int j = threadIdx.x;   // 64 threads
  int cnt = start[g+1] - start[g]; if (cnt < 1) cnt = 1;
  float inv = 1.f/(float)cnt;
  if (j < H){
    if (LAYER == 0){
      float mx = gxy[2*g]*inv, my = gxy[2*g+1]*inv;
      glob[j] = b_init[j] + mx*w_init[j] + my*w_init[H+j];
    } else {
      glob[j] = gsum[g*H+j]*inv*stats[j] + stats[H+j];   // a1, c1
    }
  }
  __syncthreads();
  if (j < H){
    const float* W = Ws1 + LAYER*100*H;   // rows 0..49 multiply glob
    float acc = bs1[LAYER*H + j];
    #pragma unroll 5
    for (int k = 0; k < H; ++k) acc = fmaf(glob[k], W[k*H + j], acc);
    tg[g*H + j] = acc;
  }
}

// ---- precompute A-fragments of W^T (f16 hi/lo planes) + zero-padded biases ----
// frag flat index = (((L*5+m)*4 + Mt)*4 + ks)*2 + pl, 64 lanes of uint2 (=half4) each.
// A layout (16x16x16): row j_out = Mt*16 + (lane&15); k_in = ks*16 + (lane>>4)*4 + e.
__global__ void k_wfrag(const float* __restrict__ Ws1, const float* __restrict__ Ws,
                        const float* __restrict__ bs,
                        uint2* __restrict__ frag, float* __restrict__ pbias){
  int t = blockIdx.x*blockDim.x + threadIdx.x;
  if (t < 20480){
    int lane = t & 63;
    int pl   = (t>>6) & 1;
    int ks   = (t>>7) & 3;
    int Mt   = (t>>9) & 3;
    int rest = t >> 11;
    int m = rest % 5, L = rest / 5;
    const float* W = (m == 0) ? (Ws1 + L*100*H + H*H) : (Ws + (L*4 + (m-1))*H*H);
    int jo = Mt*16 + (lane & 15);
    int kb = ks*16 + ((lane>>4)<<2);
    f32x4 v;
    #pragma unroll
    for (int e = 0; e < 4; ++e){
      int k = kb + e;
      v[e] = (k < H && jo < H) ? W[k*H + jo] : 0.f;   // zero-pad kills 50->64 pad
    }
    H4 hh, hl;
    split4(v, hh, hl);
    frag[t] = pl ? hl.u : hh.u;
  } else if (t < 20992){
    int i = t - 20480;           // i = (L*4+mi)*64 + j
    int j = i & 63;
    int row = i >> 6;            // L*4 + mi
    pbias[i] = (j < H) ? bs[row*H + j] : 0.f;
  }
}

template<int LAYER>
__global__ __launch_bounds__(256, 3)
void k_layer(const float2* __restrict__ xy, const int* __restrict__ sid,
             const float* __restrict__ tg, const uint2* __restrict__ frag,
             const float* __restrict__ pbias,
             const float* __restrict__ w_init, const float* __restrict__ b_init,
             const float* __restrict__ stats,
             float* __restrict__ xio, int N)
{
  const int tid = threadIdx.x;
  const int wv = tid >> 6, l = tid & 63, lg = l >> 4, ll = l & 15;
  const int base = blockIdx.x*128 + wv*32;     // 32 nodes per wave, 4 waves/block

  // ---- B-fragments for matvec 0: col n = node = Nt*16+ll, k = ks*16 + lg*4 + e ----
  H4 bh[2][4], bl[2][4];
  #pragma unroll
  for (int Nt = 0; Nt < 2; ++Nt){
    int node = base + Nt*16 + ll;
    int nc = node < N ? node : N-1;
    float xv[16];
    if (LAYER == 0){
      float2 p = xy[nc];
      #pragma unroll
      for (int ks = 0; ks < 4; ++ks)
        #pragma unroll
        for (int e = 0; e < 4; ++e){
          int k = ks*16 + lg*4 + e; int kc = k < H ? k : H-1;   // pad -> finite garbage, W-zeros kill it
          xv[ks*4+e] = b_init[kc] + p.x*w_init[kc] + p.y*w_init[H+kc];
        }
    } else {
      #pragma unroll
      for (int ks = 0; ks < 4; ++ks){
        int k0 = ks*16 + lg*4;
        size_t f0 = (size_t)nc*H + k0;
        size_t fm = (size_t)N*H - 2;
        float2 u0 = *(const float2*)(xio + (f0     < fm ? f0     : fm));
        float2 u1 = *(const float2*)(xio + (f0 + 2 < fm ? f0 + 2 : fm));
        float vv[4] = {u0.x, u0.y, u1.x, u1.y};
        #pragma unroll
        for (int e = 0; e < 4; ++e){
          int kc = (k0+e) < H ? (k0+e) : H-1;
          xv[ks*4+e] = vv[e]*stats[kc] + stats[H+kc];          // BN1 affine on the way in
        }
      }
    }
    #pragma unroll
    for (int ks = 0; ks < 4; ++ks){
      f32x4 v; v[0]=xv[ks*4]; v[1]=xv[ks*4+1]; v[2]=xv[ks*4+2]; v[3]=xv[ks*4+3];
      split4(v, bh[Nt][ks], bl[Nt][ks]);
    }
  }

  // ---- acc init = tg[g] (per-graph glob part + bs1, fp32-exact) ----
  // D layout: col n = node = Nt*16+ll, row j = Mt*16 + lg*4 + r
  f32x4 acc[4][2];
  {
    int n0 = base + ll;       n0 = n0 < N ? n0 : N-1;
    int n1 = base + 16 + ll;  n1 = n1 < N ? n1 : N-1;
    const float* t0 = tg + (size_t)sid[n0]*H;
    const float* t1 = tg + (size_t)sid[n1]*H;
    #pragma unroll
    for (int Mt = 0; Mt < 4; ++Mt)
      #pragma unroll
      for (int r = 0; r < 4; ++r){
        int j = Mt*16 + lg*4 + r; int jc = j < H ? j : H-1;
        acc[Mt][0][r] = t0[jc];
        acc[Mt][1][r] = t1[jc];
      }
  }

  // ---- 5 chained matvecs; output regs become next B-frags (no LDS, no shuffles) ----
  #pragma unroll
  for (int m = 0; m < 5; ++m){
    const uint2* fp = frag + (LAYER*5 + m)*2048;
    #pragma unroll
    for (int Mt = 0; Mt < 4; ++Mt){
      H4 ah[4], al[4];
      #pragma unroll
      for (int ks = 0; ks < 4; ++ks){
        ah[ks].u = fp[Mt*512 + ks*128 + l];         // hi plane
        al[ks].u = fp[Mt*512 + ks*128 + 64 + l];    // lo plane
      }
      #pragma unroll
      for (int Nt = 0; Nt < 2; ++Nt){
        f32x4 c = acc[Mt][Nt];
        #pragma unroll
        for (int ks = 0; ks < 4; ++ks) c = mfma16(ah[ks].h, bh[Nt][ks].h, c);  // Wh*xh
        #pragma unroll
        for (int ks = 0; ks < 4; ++ks) c = mfma16(al[ks].h, bh[Nt][ks].h, c);  // Wl*xh
        #pragma unroll
        for (int ks = 0; ks < 4; ++ks) c = mfma16(ah[ks].h, bl[Nt][ks].h, c);  // Wh*xl
        acc[Mt][Nt] = c;
      }
    }
    if (m < 4){
      // relu -> split -> B-frags in place (kstep of next matvec = Mt of this output)
      #pragma unroll
      for (int Mt = 0; Mt < 4; ++Mt){
        const f32x4 bv = *(const f32x4*)(pbias + (LAYER*4 + m)*64 + Mt*16 + (lg<<2));
        #pragma unroll
        for (int Nt = 0; Nt < 2; ++Nt){
          f32x4 v = acc[Mt][Nt];
          v[0]=fmaxf(v[0],0.f); v[1]=fmaxf(v[1],0.f); v[2]=fmaxf(v[2],0.f); v[3]=fmaxf(v[3],0.f);
          split4(v, bh[Nt][Mt], bl[Nt][Mt]);
          acc[Mt][Nt] = bv;                          // bias of next matvec
        }
      }
    }
  }

  // ---- store final matvec output (no relu), only j < 50 ----
  #pragma unroll
  for (int Nt = 0; Nt < 2; ++Nt){
    int node = base + Nt*16 + ll;
    if (node < N){
      float* row = xio + (size_t)node*H;
      #pragma unroll
      for (int Mt = 0; Mt < 3; ++Mt){
        int j0 = Mt*16 + (lg<<2);
        *(float2*)(row + j0)     = make_float2(acc[Mt][Nt][0], acc[Mt][Nt][1]);
        *(float2*)(row + j0 + 2) = make_float2(acc[Mt][Nt][2], acc[Mt][Nt][3]);
      }
      if (lg == 0)
        *(float2*)(row + 48) = make_float2(acc[3][Nt][0], acc[3][Nt][1]);
    }
  }
}

__global__ void k_stats(const float* __restrict__ x, const int* __restrict__ start,
                        float* __restrict__ gsum, float* __restrict__ psum,
                        float* __restrict__ psq){
  int g = blockIdx.x; int j = threadIdx.x;   // 64 threads, 50 active
  if (j >= H) return;
  int s = start[g], e = start[g+1];
  float acc = 0.f, q = 0.f;
  for (int n = s; n < e; ++n){ float v = x[n*H + j]; acc += v; q = fmaf(v, v, q); }
  gsum[g*H + j] = acc;
  int slot = g & 63;
  atomicAdd(&psum[slot*H + j], acc);
  atomicAdd(&psq[slot*H + j], q);
}

__global__ void k_finalize(const float* __restrict__ psum, const float* __restrict__ psq,
                           const float* __restrict__ gamma, const float* __restrict__ beta,
                           int layer, float ninv, float* __restrict__ stats){
  int j = threadIdx.x;
  if (j >= H) return;
  float s = 0.f, q = 0.f;
  #pragma unroll 8
  for (int p = 0; p < 64; ++p){ s += psum[p*H + j]; q += psq[p*H + j]; }
  float mu  = s*ninv;
  float var = q*ninv - mu*mu;
  float a = rsqrtf(var + EPSV) * gamma[layer*H + j];
  float c = beta[layer*H + j] - mu*a;
  stats[layer*100 + j]     = a;
  stats[layer*100 + H + j] = c;
}

__global__ void k_bnapply(float* __restrict__ x, const float* __restrict__ stats, int N){
  __shared__ float a[H], c[H];
  if (threadIdx.x < H){ a[threadIdx.x] = stats[100 + threadIdx.x]; c[threadIdx.x] = stats[150 + threadIdx.x]; }
  __syncthreads();
  int base = blockIdx.x * (256*H);    // block covers 256 nodes -> base % 50 == 0
  int total = N*H;
  for (int idx = threadIdx.x; idx < 256*H; idx += 256){
    int i = base + idx;
    if (i < total){
      int j = idx - (idx/H)*H;
      x[i] = x[i]*a[j] + c[j];
    }
  }
}

extern "C" void kernel_launch(void* const* d_in, const int* in_sizes, int n_in,
                              void* d_out, int out_size, void* d_ws, size_t ws_size,
                              hipStream_t stream) {
  const float2* xy     = (const float2*)d_in[0];
  const int*    sid    = (const int*)d_in[1];
  const float*  w_init = (const float*)d_in[3];
  const float*  b_init = (const float*)d_in[4];
  const float*  Ws1    = (const float*)d_in[5];
  const float*  bs1    = (const float*)d_in[6];
  const float*  Ws     = (const float*)d_in[7];
  const float*  bs     = (const float*)d_in[8];
  const float*  gamma  = (const float*)d_in[9];
  const float*  beta   = (const float*)d_in[10];
  float* out = (float*)d_out;
  int N = in_sizes[0] / 2;
  const int G = GN;

  char* ws = (char*)d_ws;
  int*   start = (int*)ws;                          // (G+1) ints
  float* gxy   = (float*)(ws + 40064);              // 2G floats
  float* tg    = (float*)(ws + 120064);             // 50G floats (2 MB)
  float* gsum  = (float*)(ws + 2120064);            // 50G floats (2 MB)
  float* psum  = (float*)(ws + 4120064);            // 64*50 floats
  float* psq   = (float*)(ws + 4132864);            // 64*50 floats
  float* stats = (float*)(ws + 4145664);            // 200 floats: a1,c1,a2,c2
  uint2* wfrag = (uint2*)(ws + 4147200);            // 163840 B of W^T fragments
  float* pbias = (float*)(ws + 4311040);            // 2048 B padded biases

  int nb = (N + 127)/128;

  k_wfrag<<<82, 256, 0, stream>>>(Ws1, Ws, bs, wfrag, pbias);
  k_start<<<(G + 1 + 255)/256, 256, 0, stream>>>(sid, N, start);
  k_gsum_xy<<<G, 64, 0, stream>>>(xy, start, gxy);
  k_tgraph<0><<<G, 64, 0, stream>>>(gxy, gsum, start, w_init, b_init, Ws1, bs1, stats, tg);
  k_layer<0><<<nb, 256, 0, stream>>>(xy, sid, tg, wfrag, pbias, w_init, b_init, stats, out, N);

  (void)hipMemsetAsync(psum, 0, 2*64*H*sizeof(float), stream);   // psum+psq contiguous
  k_stats<<<G, 64, 0, stream>>>(out, start, gsum, psum, psq);
  k_finalize<<<1, 64, 0, stream>>>(psum, psq, gamma, beta, 0, 1.0f/(float)N, stats);

  k_tgraph<1><<<G, 64, 0, stream>>>(gxy, gsum, start, w_init, b_init, Ws1, bs1, stats, tg);
  k_layer<1><<<nb, 256, 0, stream>>>(xy, sid, tg, wfrag, pbias, w_init, b_init, stats, out, N);

  (void)hipMemsetAsync(psum, 0, 2*64*H*sizeof(float), stream);
  k_stats<<<G, 64, 0, stream>>>(out, start, gsum, psum, psq);
  k_finalize<<<1, 64, 0, stream>>>(psum, psq, gamma, beta, 1, 1.0f/(float)N, stats);

  k_bnapply<<<(N + 255)/256, 256, 0, stream>>>(out, stats, N);
}

// Round 4
// 731.027 us; speedup vs baseline: 3.3678x; 1.1484x over previous
//
#include <hip/hip_runtime.h>

// DeepSet: N=1M nodes, G=10k graphs (sorted segment ids), HIDDEN=50, 2 layers.
// v4: 8-dispatch pipeline.
//   k_pre      : W^T MFMA fragments (f16 hi/lo, uint4-interleaved) + padded biases
//                + start[] binary search + psum/psq zeroing
//   k_ginit0   : per-graph xy mean (wave reduce) + tg = glob@Ws1[0][:50]+bs1[0]
//   k_layer<L> : register-resident MFMA matvec chain (v_mfma_f32_16x16x16_f16,
//                fp32 emu: xh@Wh + xl@Wh + xh@Wl); epilogue computes BN sum/sumsq
//                from registers (shfl_xor reduce + 64-slot atomics) -- no k_stats.
//   k_finalize : a,c from psum/psq; re-zeros psum/psq for next layer
//   k_gt1      : per-graph sum of x1 (gsum) -> BN1 affine -> tg for layer 2
//   k_bnapply  : out = out*a2 + c2

#define GN 10000
#define H 50
#define EPSV 1e-5f

typedef __attribute__((ext_vector_type(4))) float f32x4;
typedef __attribute__((ext_vector_type(2))) __fp16 fp16x2;
typedef __attribute__((ext_vector_type(4))) _Float16 half4_t;

union H4 { half4_t h; uint2 u; };

static __device__ __forceinline__ f32x4 mfma16(half4_t a, half4_t b, f32x4 c){
#if __has_builtin(__builtin_amdgcn_mfma_f32_16x16x16f16)
  return __builtin_amdgcn_mfma_f32_16x16x16f16(a, b, c, 0, 0, 0);
#else
  asm volatile("v_mfma_f32_16x16x16_f16 %0, %1, %2, %0" : "+v"(c) : "v"(a), "v"(b));
  return c;
#endif
}

// split fp32x4 into f16 hi plane + f16 residual plane
static __device__ __forceinline__ void split4(f32x4 v, H4& hh, H4& hl){
  fp16x2 a = __builtin_amdgcn_cvt_pkrtz(v[0], v[1]);
  fp16x2 b = __builtin_amdgcn_cvt_pkrtz(v[2], v[3]);
  hh.u.x = __builtin_bit_cast(unsigned int, a);
  hh.u.y = __builtin_bit_cast(unsigned int, b);
  float r0 = v[0] - (float)a[0];
  float r1 = v[1] - (float)a[1];
  float r2 = v[2] - (float)b[0];
  float r3 = v[3] - (float)b[1];
  fp16x2 c = __builtin_amdgcn_cvt_pkrtz(r0, r1);
  fp16x2 d = __builtin_amdgcn_cvt_pkrtz(r2, r3);
  hl.u.x = __builtin_bit_cast(unsigned int, c);
  hl.u.y = __builtin_bit_cast(unsigned int, d);
}

// ---- fused prepass: W fragments + padded biases + start[] + psum/psq zero ----
// frag uint4 layout: t = ((L*5+m)*4 + Mt)*4*64 + ks*64 + lane;
//   .xy = hi plane (4 f16), .zw = lo plane. A layout (16x16x16):
//   row j_out = Mt*16 + (lane&15); k_in = ks*16 + (lane>>4)*4 + e.
__global__ void k_pre(const float* __restrict__ Ws1, const float* __restrict__ Ws,
                      const float* __restrict__ bs, const int* __restrict__ sid, int N,
                      uint4* __restrict__ frag, float* __restrict__ pbias,
                      int* __restrict__ start, float* __restrict__ pzero){
  int t = blockIdx.x*blockDim.x + threadIdx.x;
  if (t < 10240){
    int lane = t & 63;
    int ks   = (t>>6) & 3;
    int Mt   = (t>>8) & 3;
    int rest = t >> 10;                 // 0..9 = L*5 + m
    int m = rest % 5, L = rest / 5;
    const float* W = (m == 0) ? (Ws1 + L*100*H + H*H) : (Ws + (L*4 + (m-1))*H*H);
    int jo = Mt*16 + (lane & 15);
    int kb = ks*16 + ((lane>>4)<<2);
    f32x4 v;
    #pragma unroll
    for (int e = 0; e < 4; ++e){
      int k = kb + e;
      v[e] = (k < H && jo < H) ? W[k*H + jo] : 0.f;   // zero-pad kills 50->64 pad
    }
    H4 hh, hl;
    split4(v, hh, hl);
    frag[t] = make_uint4(hh.u.x, hh.u.y, hl.u.x, hl.u.y);
  } else if (t < 10752){
    int i = t - 10240;                  // (L*4+mi)*64 + j, 512 entries
    int j = i & 63;
    int row = i >> 6;
    pbias[i] = (j < H) ? bs[row*H + j] : 0.f;
  } else if (t < 20753){
    int g = t - 10752;                  // 0..10000
    int lo = 0, hi = N;
    while (lo < hi){ int mid = (lo+hi)>>1; if (sid[mid] < g) lo = mid+1; else hi = mid; }
    start[g] = lo;
  } else if (t >= 20800 && t < 27200){
    pzero[t - 20800] = 0.f;             // psum+psq contiguous, 6400 floats
  }
}

// ---- per-graph: xy mean + tg for layer 0 ----
__global__ void k_ginit0(const float2* __restrict__ xy, const int* __restrict__ start,
                         const float* __restrict__ w_init, const float* __restrict__ b_init,
                         const float* __restrict__ Ws1, const float* __restrict__ bs1,
                         float* __restrict__ tg){
  __shared__ float glob[H];
  int g = blockIdx.x; int l = threadIdx.x;     // 64 threads = 1 wave
  int s = start[g], e = start[g+1];
  float sx = 0.f, sy = 0.f;
  for (int n = s + l; n < e; n += 64){ float2 v = xy[n]; sx += v.x; sy += v.y; }
  #pragma unroll
  for (int off = 32; off > 0; off >>= 1){ sx += __shfl_xor(sx, off); sy += __shfl_xor(sy, off); }
  int cnt = e - s; if (cnt < 1) cnt = 1;
  float inv = 1.f/(float)cnt;
  if (l < H) glob[l] = b_init[l] + sx*inv*w_init[l] + sy*inv*w_init[H+l];
  __syncthreads();
  if (l < H){
    float a = bs1[l];
    #pragma unroll 5
    for (int k = 0; k < H; ++k) a = fmaf(glob[k], Ws1[k*H + l], a);
    tg[(size_t)g*H + l] = a;
  }
}

template<int LAYER>
__global__ __launch_bounds__(256, 3)
void k_layer(const float2* __restrict__ xy, const int* __restrict__ sid,
             const float* __restrict__ tg, const uint4* __restrict__ frag,
             const float* __restrict__ pbias,
             const float* __restrict__ w_init, const float* __restrict__ b_init,
             const float* __restrict__ stats,
             float* __restrict__ psum, float* __restrict__ psq,
             float* __restrict__ xio, int N)
{
  const int tid = threadIdx.x;
  const int wv = tid >> 6, l = tid & 63, lg = l >> 4, ll = l & 15;
  const int base = blockIdx.x*128 + wv*32;     // 32 nodes per wave, 4 waves/block

  // ---- B-fragments for matvec 0: col n = node = Nt*16+ll, k = ks*16 + lg*4 + e ----
  H4 bh[2][4], bl[2][4];
  #pragma unroll
  for (int Nt = 0; Nt < 2; ++Nt){
    int node = base + Nt*16 + ll;
    int nc = node < N ? node : N-1;
    float xv[16];
    if (LAYER == 0){
      float2 p = xy[nc];
      #pragma unroll
      for (int ks = 0; ks < 4; ++ks)
        #pragma unroll
        for (int e = 0; e < 4; ++e){
          int k = ks*16 + lg*4 + e; int kc = k < H ? k : H-1;   // pad -> finite garbage, W-zeros kill it
          xv[ks*4+e] = b_init[kc] + p.x*w_init[kc] + p.y*w_init[H+kc];
        }
    } else {
      #pragma unroll
      for (int ks = 0; ks < 4; ++ks){
        int k0 = ks*16 + lg*4;
        size_t f0 = (size_t)nc*H + k0;
        size_t fm = (size_t)N*H - 2;
        float2 u0 = *(const float2*)(xio + (f0     < fm ? f0     : fm));
        float2 u1 = *(const float2*)(xio + (f0 + 2 < fm ? f0 + 2 : fm));
        float vv[4] = {u0.x, u0.y, u1.x, u1.y};
        #pragma unroll
        for (int e = 0; e < 4; ++e){
          int kc = (k0+e) < H ? (k0+e) : H-1;
          xv[ks*4+e] = vv[e]*stats[kc] + stats[H+kc];          // BN1 affine on the way in
        }
      }
    }
    #pragma unroll
    for (int ks = 0; ks < 4; ++ks){
      f32x4 v; v[0]=xv[ks*4]; v[1]=xv[ks*4+1]; v[2]=xv[ks*4+2]; v[3]=xv[ks*4+3];
      split4(v, bh[Nt][ks], bl[Nt][ks]);
    }
  }

  // ---- acc init = tg[g] (per-graph glob part + bs1, fp32-exact) ----
  // D layout: col n = node = Nt*16+ll, row j = Mt*16 + lg*4 + r
  f32x4 acc[4][2];
  {
    int n0 = base + ll;       n0 = n0 < N ? n0 : N-1;
    int n1 = base + 16 + ll;  n1 = n1 < N ? n1 : N-1;
    const float* t0 = tg + (size_t)sid[n0]*H;
    const float* t1 = tg + (size_t)sid[n1]*H;
    #pragma unroll
    for (int Mt = 0; Mt < 4; ++Mt)
      #pragma unroll
      for (int r = 0; r < 4; ++r){
        int j = Mt*16 + lg*4 + r; int jc = j < H ? j : H-1;
        acc[Mt][0][r] = t0[jc];
        acc[Mt][1][r] = t1[jc];
      }
  }

  // ---- 5 chained matvecs; output regs become next B-frags (no LDS, no shuffles) ----
  #pragma unroll
  for (int m = 0; m < 5; ++m){
    const uint4* fp = frag + (LAYER*5 + m)*1024;
    #pragma unroll
    for (int Mt = 0; Mt < 4; ++Mt){
      H4 ah[4], al[4];
      #pragma unroll
      for (int ks = 0; ks < 4; ++ks){
        uint4 w = fp[(Mt*4 + ks)*64 + l];          // one dwordx4: hi + lo planes
        ah[ks].u = make_uint2(w.x, w.y);
        al[ks].u = make_uint2(w.z, w.w);
      }
      #pragma unroll
      for (int Nt = 0; Nt < 2; ++Nt){
        f32x4 c = acc[Mt][Nt];
        #pragma unroll
        for (int ks = 0; ks < 4; ++ks) c = mfma16(ah[ks].h, bh[Nt][ks].h, c);  // Wh*xh
        #pragma unroll
        for (int ks = 0; ks < 4; ++ks) c = mfma16(al[ks].h, bh[Nt][ks].h, c);  // Wl*xh
        #pragma unroll
        for (int ks = 0; ks < 4; ++ks) c = mfma16(ah[ks].h, bl[Nt][ks].h, c);  // Wh*xl
        acc[Mt][Nt] = c;
      }
    }
    if (m < 4){
      // relu -> split -> B-frags in place (kstep of next matvec = Mt of this output)
      #pragma unroll
      for (int Mt = 0; Mt < 4; ++Mt){
        const f32x4 bv = *(const f32x4*)(pbias + (LAYER*4 + m)*64 + Mt*16 + (lg<<2));
        #pragma unroll
        for (int Nt = 0; Nt < 2; ++Nt){
          f32x4 v = acc[Mt][Nt];
          v[0]=fmaxf(v[0],0.f); v[1]=fmaxf(v[1],0.f); v[2]=fmaxf(v[2],0.f); v[3]=fmaxf(v[3],0.f);
          split4(v, bh[Nt][Mt], bl[Nt][Mt]);
          acc[Mt][Nt] = bv;                          // bias of next matvec
        }
      }
    }
  }

  // ---- store final matvec output (no relu), only j < 50 ----
  #pragma unroll
  for (int Nt = 0; Nt < 2; ++Nt){
    int node = base + Nt*16 + ll;
    if (node < N){
      float* row = xio + (size_t)node*H;
      #pragma unroll
      for (int Mt = 0; Mt < 3; ++Mt){
        int j0 = Mt*16 + (lg<<2);
        *(float2*)(row + j0)     = make_float2(acc[Mt][Nt][0], acc[Mt][Nt][1]);
        *(float2*)(row + j0 + 2) = make_float2(acc[Mt][Nt][2], acc[Mt][Nt][3]);
      }
      if (lg == 0)
        *(float2*)(row + 48) = make_float2(acc[3][Nt][0], acc[3][Nt][1]);
    }
  }

  // ---- fused BN-stats epilogue: psum/psq from registers ----
  // per (Mt,r): j fixed per lane-group; reduce over 16 ll-lanes (2 nodes each)
  {
    int slot = (int)(blockIdx.x & 63);
    #pragma unroll
    for (int Mt = 0; Mt < 4; ++Mt)
      #pragma unroll
      for (int r = 0; r < 4; ++r){
        int j = Mt*16 + lg*4 + r;
        float s = 0.f, q = 0.f;
        #pragma unroll
        for (int Nt = 0; Nt < 2; ++Nt){
          int node = base + Nt*16 + ll;
          float v = (node < N && j < H) ? acc[Mt][Nt][r] : 0.f;
          s += v; q = fmaf(v, v, q);
        }
        #pragma unroll
        for (int off = 8; off > 0; off >>= 1){ s += __shfl_xor(s, off); q += __shfl_xor(q, off); }
        if (ll == 0 && j < H){
          atomicAdd(&psum[slot*H + j], s);
          atomicAdd(&psq [slot*H + j], q);
        }
      }
  }
}

__global__ void k_finalize(float* __restrict__ psum, float* __restrict__ psq,
                           const float* __restrict__ gamma, const float* __restrict__ beta,
                           int layer, float ninv, float* __restrict__ stats){
  int j = threadIdx.x;
  if (j >= H) return;
  float s = 0.f, q = 0.f;
  #pragma unroll 8
  for (int p = 0; p < 64; ++p){ s += psum[p*H + j]; q += psq[p*H + j]; }
  float mu  = s*ninv;
  float var = q*ninv - mu*mu;
  float a = rsqrtf(var + EPSV) * gamma[layer*H + j];
  float c = beta[layer*H + j] - mu*a;
  stats[layer*100 + j]     = a;
  stats[layer*100 + H + j] = c;
  // re-zero for next layer's atomics (each (p,j) read only by this thread)
  #pragma unroll 8
  for (int p = 0; p < 64; ++p){ psum[p*H + j] = 0.f; psq[p*H + j] = 0.f; }
}

// ---- per-graph: gsum of x1 -> BN1 affine -> tg for layer 2 ----
__global__ void k_gt1(const float* __restrict__ x, const int* __restrict__ start,
                      const float* __restrict__ stats,
                      const float* __restrict__ Ws1, const float* __restrict__ bs1,
                      float* __restrict__ tg){
  __shared__ float glob[H];
  int g = blockIdx.x; int j = threadIdx.x;     // 64 threads, 50 active
  int s = start[g], e = start[g+1];
  int cnt = e - s; if (cnt < 1) cnt = 1;
  float inv = 1.f/(float)cnt;
  if (j < H){
    float acc = 0.f;
    for (int n = s; n < e; ++n) acc += x[(size_t)n*H + j];
    glob[j] = acc*inv*stats[j] + stats[H+j];   // a1, c1
  }
  __syncthreads();
  if (j < H){
    const float* W = Ws1 + 100*H;              // Ws1[1] rows 0..49
    float a = bs1[H + j];
    #pragma unroll 5
    for (int k = 0; k < H; ++k) a = fmaf(glob[k], W[k*H + j], a);
    tg[(size_t)g*H + j] = a;
  }
}

__global__ void k_bnapply(float* __restrict__ x, const float* __restrict__ stats, int N){
  __shared__ float a[H], c[H];
  if (threadIdx.x < H){ a[threadIdx.x] = stats[100 + threadIdx.x]; c[threadIdx.x] = stats[150 + threadIdx.x]; }
  __syncthreads();
  int base = blockIdx.x * (256*H);    // block covers 256 nodes -> base % 50 == 0
  int total = N*H;
  for (int idx = threadIdx.x; idx < 256*H; idx += 256){
    int i = base + idx;
    if (i < total){
      int j = idx - (idx/H)*H;
      x[i] = x[i]*a[j] + c[j];
    }
  }
}

extern "C" void kernel_launch(void* const* d_in, const int* in_sizes, int n_in,
                              void* d_out, int out_size, void* d_ws, size_t ws_size,
                              hipStream_t stream) {
  const float2* xy     = (const float2*)d_in[0];
  const int*    sid    = (const int*)d_in[1];
  const float*  w_init = (const float*)d_in[3];
  const float*  b_init = (const float*)d_in[4];
  const float*  Ws1    = (const float*)d_in[5];
  const float*  bs1    = (const float*)d_in[6];
  const float*  Ws     = (const float*)d_in[7];
  const float*  bs     = (const float*)d_in[8];
  const float*  gamma  = (const float*)d_in[9];
  const float*  beta   = (const float*)d_in[10];
  float* out = (float*)d_out;
  int N = in_sizes[0] / 2;
  const int G = GN;

  char* ws = (char*)d_ws;
  int*   start = (int*)ws;                      // 40,004 B          [0 .. 40064)
  float* tg    = (float*)(ws + 40064);          // 50G floats (2 MB) [.. 2040064)
  float* psum  = (float*)(ws + 2040064);        // 64*50 floats      [.. 2052864)
  float* psq   = (float*)(ws + 2052864);        // 64*50 floats      [.. 2065664)
  float* stats = (float*)(ws + 2065664);        // 200 floats        [.. 2066464)
  uint4* frag  = (uint4*)(ws + 2066560);        // 163,840 B         [.. 2230400)
  float* pbias = (float*)(ws + 2230400);        // 2,048 B

  int nb = (N + 127)/128;

  k_pre<<<107, 256, 0, stream>>>(Ws1, Ws, bs, sid, N, frag, pbias, start, psum);
  k_ginit0<<<G, 64, 0, stream>>>(xy, start, w_init, b_init, Ws1, bs1, tg);
  k_layer<0><<<nb, 256, 0, stream>>>(xy, sid, tg, frag, pbias, w_init, b_init, stats, psum, psq, out, N);
  k_finalize<<<1, 64, 0, stream>>>(psum, psq, gamma, beta, 0, 1.0f/(float)N, stats);
  k_gt1<<<G, 64, 0, stream>>>(out, start, stats, Ws1, bs1, tg);
  k_layer<1><<<nb, 256, 0, stream>>>(xy, sid, tg, frag, pbias, w_init, b_init, stats, psum, psq, out, N);
  k_finalize<<<1, 64, 0, stream>>>(psum, psq, gamma, beta, 1, 1.0f/(float)N, stats);
  k_bnapply<<<(N + 255)/256, 256, 0, stream>>>(out, stats, N);
}